// Round 6
// baseline (41.818 us; speedup 1.0000x reference)
//
#include <hip/hip_runtime.h>
#include <hip/hip_fp16.h>
#include <stdint.h>

#define TOKENS 2048
#define DIM    2048
#define GROUP  128

typedef _Float16 half_t;
typedef __attribute__((ext_vector_type(4)))  _Float16 f16x4;
typedef __attribute__((ext_vector_type(8)))  _Float16 f16x8;
typedef __attribute__((ext_vector_type(4)))  float    f32x4;
typedef __attribute__((ext_vector_type(16))) float    f32x16;

// ---------------- quantization ----------------

__device__ __forceinline__ float group32_sum(float v) {
#pragma unroll
  for (int off = 16; off > 0; off >>= 1)
    v += __shfl_xor(v, off, 64);
  return v;
}

__device__ __forceinline__ float nearest_q(float u) {
  float qi = fminf(fmaxf(rintf(u * 0.25f) * 4.0f, -28.0f), 28.0f);
  float a = fabsf(u);
  float m = a <= 56.f  ? 48.f
          : a <= 80.f  ? 64.f
          : a <= 112.f ? 96.f
          : a <= 160.f ? 128.f
          : a <= 224.f ? 192.f
          : a <= 320.f ? 256.f : 384.f;
  float qo = copysignf(m, u);
  return (fabsf(u - qo) < fabsf(u - qi)) ? qo : qi;
}

__global__ __launch_bounds__(256) void quant2_kernel(
    const float* __restrict__ x, const float* __restrict__ w,
    half_t* __restrict__ out) {
  const int wid  = threadIdx.x >> 6;
  const int lane = threadIdx.x & 63;
  const int l    = lane & 31;
  const int g    = blockIdx.x * 8 + wid * 2 + (lane >> 5);
  const int NG1  = TOKENS * DIM / GROUP;   // 32768

  const float alpha = (g < NG1) ? 0.9f : 1.0f;
  const float* src  = (g < NG1) ? x : w;
  const size_t sbase = (size_t)(g < NG1 ? g : g - NG1) * GROUP + l * 4;

  const float4 v = *reinterpret_cast<const float4*>(src + sbase);

  const float mean = group32_sum(v.x + v.y + v.z + v.w) * (1.0f / 128.0f);
  const float d0 = v.x - mean, d1 = v.y - mean, d2 = v.z - mean, d3 = v.w - mean;
  const float var = group32_sum(d0 * d0 + d1 * d1 + d2 * d2 + d3 * d3) *
                    (1.0f / 127.0f);
  const float scale = (fabsf(mean) + 3.0f * sqrtf(var)) * alpha / 28.0f;
  const float rs = 1.0f / scale;

  float q0 = nearest_q(v.x * rs);
  float q1 = nearest_q(v.y * rs);
  float q2 = nearest_q(v.z * rs);
  float q3 = nearest_q(v.w * rs);
  if (fabsf(q0) > 32.0f)      q1 = 0.0f;
  else if (fabsf(q1) > 32.0f) q0 = 0.0f;
  if (fabsf(q2) > 32.0f)      q3 = 0.0f;
  else if (fabsf(q3) > 32.0f) q2 = 0.0f;

  f16x4 hv;
  hv.x = (half_t)(q0 * scale);
  hv.y = (half_t)(q1 * scale);
  hv.z = (half_t)(q2 * scale);
  hv.w = (half_t)(q3 * scale);
  *reinterpret_cast<f16x4*>(out + (size_t)g * GROUP + l * 4) = hv;
}

// ---------------- GEMM: C[m,n] = sum_k A[m,k] * B[n,k] ----------------
// BM=BN=128, BK=64. 512 threads = 8 waves: (wc in {0,1}) x (wz in {0..3}).
// Wave tile 128x64 (af[4]+bf[2] -> 6 LDS reads per 8 MFMA, ratio 0.75),
// 4-way split-K: wave wz handles K=16 slice wz of each BK=64 step.
// 4-deep LDS pipeline (4 x 32 KB), ONE barrier per iteration:
//   vmcnt(8) -> s_barrier -> stage(j+3) -> compute(j)
// (barrier proves compute(j-1) done before stage overwrites buf[(j-1)%4];
//  counted vmcnt keeps 2 stages in flight across it.)
// XOR swizzle ((row&7)<<4) both-sides (T2, rule 21); XCD 8x4 chunk swizzle.
// Epilogue: 2-level LDS tree reduction over wz, then wz=0 stores.

#define BM 128
#define BN 128
#define BK 64

__device__ __forceinline__ void gload_lds16(const half_t* g, half_t* l) {
  __builtin_amdgcn_global_load_lds(
      (__attribute__((address_space(1))) uint32_t*)g,
      (__attribute__((address_space(3))) uint32_t*)l, 16, 0, 0);
}

__global__ __launch_bounds__(512, 2) void gemm_kernel(
    const half_t* __restrict__ A, const half_t* __restrict__ B,
    float* __restrict__ C) {
  __shared__ char lds_raw[4 * 32768];   // 128 KB

  const int tid  = threadIdx.x;
  const int lane = tid & 63;
  const int wid  = tid >> 6;           // 0..7
  const int wc   = wid >> 2;           // 0..1  N-half
  const int wz   = wid & 3;            // 0..3  K-slice

  const int bid = blockIdx.x;
  const int c   = bid & 7;
  const int idx = bid >> 3;
  const int bm  = ((c >> 2) << 3) + (idx >> 2);
  const int bn  = ((c & 3) << 2) + (idx & 3);

  const half_t* gA = A + (size_t)(bm * BM) * DIM;
  const half_t* gB = B + (size_t)(bn * BN) * DIM;

  auto stage = [&](char* buf, int kt) {
#pragma unroll
    for (int i = 0; i < 2; ++i) {      // A: 16 KB
      int P   = (i * 512 + tid) * 16;
      int row = P >> 7;
      int cb  = (P & 127) ^ ((row & 7) << 4);
      gload_lds16(gA + (size_t)row * DIM + kt * BK + (cb >> 1),
                  (half_t*)(buf + P));
    }
#pragma unroll
    for (int i = 0; i < 2; ++i) {      // B: 16 KB
      int P   = (i * 512 + tid) * 16;
      int row = P >> 7;
      int cb  = (P & 127) ^ ((row & 7) << 4);
      gload_lds16(gB + (size_t)row * DIM + kt * BK + (cb >> 1),
                  (half_t*)(buf + 16384 + P));
    }
  };

  f32x16 acc[4][2] = {};

  auto compute = [&](const char* buf) {
    const char* cA = buf;
    const char* cB = buf + 16384;
    const int r31 = lane & 31;
    const int swzv = (r31 & 7) << 4;
    const int cb = wz * 32 + ((lane >> 5) << 4);   // this wave's K=16 slice
    const int pc = cb ^ swzv;
    f16x8 af[4], bf[2];
#pragma unroll
    for (int mt = 0; mt < 4; ++mt) {
      int row = mt * 32 + r31;
      af[mt] = *reinterpret_cast<const f16x8*>(cA + (row << 7) + pc);
    }
#pragma unroll
    for (int nt = 0; nt < 2; ++nt) {
      int row = wc * 64 + nt * 32 + r31;
      bf[nt] = *reinterpret_cast<const f16x8*>(cB + (row << 7) + pc);
    }
    __builtin_amdgcn_s_setprio(1);
#pragma unroll
    for (int mt = 0; mt < 4; ++mt)
#pragma unroll
      for (int nt = 0; nt < 2; ++nt)
        acc[mt][nt] = __builtin_amdgcn_mfma_f32_32x32x16_f16(
            af[mt], bf[nt], acc[mt][nt], 0, 0, 0);
    __builtin_amdgcn_s_setprio(0);
  };

  char* S0 = lds_raw;
  char* S1 = lds_raw + 32768;
  char* S2 = lds_raw + 65536;
  char* S3 = lds_raw + 98304;

  stage(S0, 0);
  stage(S1, 1);
  stage(S2, 2);

  auto iterS = [&](char* cbuf, char* sbuf, int ktstage) {
    asm volatile("s_waitcnt vmcnt(8)" ::: "memory");
    __builtin_amdgcn_s_barrier();
    stage(sbuf, ktstage);
    compute(cbuf);
  };

  for (int base = 0; base < 28; base += 4) {   // j = 0..27
    iterS(S0, S3, base + 3);
    iterS(S1, S0, base + 4);
    iterS(S2, S1, base + 5);
    iterS(S3, S2, base + 6);
  }
  iterS(S0, S3, 31);                           // j = 28
  asm volatile("s_waitcnt vmcnt(8)" ::: "memory");   // j = 29
  __builtin_amdgcn_s_barrier();
  compute(S1);
  asm volatile("s_waitcnt vmcnt(4)" ::: "memory");   // j = 30
  __builtin_amdgcn_s_barrier();
  compute(S2);
  asm volatile("s_waitcnt vmcnt(0)" ::: "memory");   // j = 31
  __builtin_amdgcn_s_barrier();
  compute(S3);

  // ---- 2-level split-K reduction over wz, in (now dead) pipeline LDS ----
  __syncthreads();
  float* red = (float*)lds_raw;
  const int reg1 = (wc * 2 + (wz >> 1)) * 8192;   // 4 x 32 KB regions

  auto dump = [&](int regbase) {
#pragma unroll
    for (int mt = 0; mt < 4; ++mt)
#pragma unroll
      for (int nt = 0; nt < 2; ++nt)
#pragma unroll
        for (int q = 0; q < 4; ++q) {
          f32x4 v;
          v.x = acc[mt][nt][q * 4 + 0];
          v.y = acc[mt][nt][q * 4 + 1];
          v.z = acc[mt][nt][q * 4 + 2];
          v.w = acc[mt][nt][q * 4 + 3];
          *reinterpret_cast<f32x4*>(
              red + regbase + (((mt * 2 + nt) * 4 + q) * 64 + lane) * 4) = v;
        }
  };
  auto addin = [&](int regbase) {
#pragma unroll
    for (int mt = 0; mt < 4; ++mt)
#pragma unroll
      for (int nt = 0; nt < 2; ++nt)
#pragma unroll
        for (int q = 0; q < 4; ++q) {
          f32x4 v = *reinterpret_cast<const f32x4*>(
              red + regbase + (((mt * 2 + nt) * 4 + q) * 64 + lane) * 4);
          acc[mt][nt][q * 4 + 0] += v.x;
          acc[mt][nt][q * 4 + 1] += v.y;
          acc[mt][nt][q * 4 + 2] += v.z;
          acc[mt][nt][q * 4 + 3] += v.w;
        }
  };

  if (wz & 1) dump(reg1);            // wz 1,3 dump
  __syncthreads();
  if (!(wz & 1)) addin(reg1);        // wz 0,2 add partner
  __syncthreads();
  if (wz == 2) dump(wc * 8192);      // level 2
  __syncthreads();
  if (wz == 0) {
    addin(wc * 8192);
    const int crow0 = bm * BM + 4 * (lane >> 5);
    const int ccol0 = bn * BN + wc * 64 + (lane & 31);
#pragma unroll
    for (int mt = 0; mt < 4; ++mt)
#pragma unroll
      for (int nt = 0; nt < 2; ++nt)
#pragma unroll
        for (int r = 0; r < 16; ++r) {
          int row = crow0 + mt * 32 + (r & 3) + 8 * (r >> 2);
          int col = ccol0 + nt * 32;
          C[(size_t)row * DIM + col] = acc[mt][nt][r];
        }
  }
}

// ---------------- launch ----------------

extern "C" void kernel_launch(void* const* d_in, const int* in_sizes, int n_in,
                              void* d_out, int out_size, void* d_ws,
                              size_t ws_size, hipStream_t stream) {
  const float* x = (const float*)d_in[0];
  const float* w = (const float*)d_in[1];
  float* out = (float*)d_out;

  half_t* xq = (half_t*)d_ws;                     // xq ++ wq, 16 MB

  const int ngroups = 2 * TOKENS * DIM / GROUP;   // 65536
  quant2_kernel<<<ngroups / 8, 256, 0, stream>>>(x, w, xq);

  half_t* wq = xq + (size_t)TOKENS * DIM;
  gemm_kernel<<<256, 512, 0, stream>>>(xq, wq, out);
}